// Round 8
// baseline (413.460 us; speedup 1.0000x reference)
//
#include <hip/hip_runtime.h>

#define N_NODES 4096
#define D_MODEL 128
#define QK_DIM  32
#define NHEAD   8
#define QKH     (QK_DIM * NHEAD)   // 256
#define VH      (D_MODEL * NHEAD)  // 1024

typedef _Float16 f16;
typedef _Float16 f16x8 __attribute__((ext_vector_type(8)));
typedef float    f32x4 __attribute__((ext_vector_type(4)));
typedef unsigned long long u64;

static __device__ __forceinline__ unsigned int pack_f16x2(float a, float b) {
    union { f16 h; unsigned short s; } ua, ub;
    ua.h = (f16)a; ub.h = (f16)b;
    return ((unsigned int)ub.s << 16) | (unsigned int)ua.s;
}

// ---- fused prep: mask->bits | x->f16 | Wq,Wk->Wqkt | Wv->Wvt | Wo->Wot ----
__global__ __launch_bounds__(256) void prep_kernel(
    const int* __restrict__ mask, u64* __restrict__ mbits,
    const float* __restrict__ x, f16* __restrict__ xf,
    const float* __restrict__ Wq, const float* __restrict__ Wk,
    f16* __restrict__ Wqkt,
    const float* __restrict__ Wv, f16* __restrict__ Wvt,
    const float* __restrict__ Wo, f16* __restrict__ Wot) {
    const int b = blockIdx.x, t = threadIdx.x;
    if (b < 1024) {
        const int gw = b * 4 + (t >> 6), lane = t & 63;
        for (int word = gw; word < 262144; word += 4096) {
            const int v = mask[(size_t)word * 64 + lane];
            const u64 bits = __ballot(v != 0);
            if (lane == 0) mbits[word] = bits;
        }
    } else if (b < 1280) {
        const int tid = (b - 1024) * 256 + t;
        const float2* x2 = (const float2*)x;
        unsigned int* u = (unsigned int*)xf;
        for (int i = tid; i < 262144; i += 65536) {
            const float2 v = x2[i];
            u[i] = pack_f16x2(v.x, v.y);
        }
    } else if (b < 1408) {
        const int tid = (b - 1280) * 256 + t;           // 32768 elems
        const int n = tid >> 7, k = tid & 127;
        Wqkt[tid] = (f16)Wq[(size_t)k * QKH + n];
    } else if (b < 1536) {
        const int tid = (b - 1408) * 256 + t;           // 32768 elems
        const int n = tid >> 7, k = tid & 127;
        Wqkt[32768 + tid] = (f16)Wk[(size_t)k * QKH + n];
    } else if (b < 2048) {
        const int tid = (b - 1536) * 256 + t;           // 131072 elems
        const int n = tid >> 7, k = tid & 127;
        Wvt[tid] = (f16)Wv[(size_t)k * VH + n];
    } else {
        const int tid = (b - 2048) * 256 + t;           // 131072 elems
        const int n = tid >> 10, k = tid & 1023;
        Wot[tid] = (f16)Wo[(size_t)k * D_MODEL + n];
    }
}

// ---- GEMM body: C[M,N] = A[M,K](f16) @ Wt[N,K]^T (+bias) -----------------
template <int OUT_MODE, bool DUAL_BIAS>
static __device__ __forceinline__ void gemm_body(
    const f16* __restrict__ A, const f16* __restrict__ Wt,
    const float* __restrict__ b1, const float* __restrict__ b2,
    void* __restrict__ outp, int M, int N, int K,
    int bx, int by, int bz, int nz) {
    const int t = threadIdx.x;
    const int w = t >> 6, lane = t & 63, quad = lane >> 4, col = lane & 15;
    const int mb = by * 64 + (w & 1) * 32;
    const int nb = bx * 64 + (w >> 1) * 32;

    const f32x4 zero = {0.f, 0.f, 0.f, 0.f};
    f32x4 acc[2][2];
    acc[0][0] = zero; acc[0][1] = zero; acc[1][0] = zero; acc[1][1] = zero;

    const int ksteps = K >> 5;
    const int kper = ksteps / nz;
    const int ks0 = bz * kper, ks1 = ks0 + kper;
    for (int ks = ks0; ks < ks1; ++ks) {
        const int ko = ks * 32 + quad * 8;
        const f16x8 a0 = *reinterpret_cast<const f16x8*>(&A[(size_t)(mb + col) * K + ko]);
        const f16x8 a1 = *reinterpret_cast<const f16x8*>(&A[(size_t)(mb + 16 + col) * K + ko]);
        const f16x8 b0 = *reinterpret_cast<const f16x8*>(&Wt[(size_t)(nb + col) * K + ko]);
        const f16x8 bb = *reinterpret_cast<const f16x8*>(&Wt[(size_t)(nb + 16 + col) * K + ko]);
        acc[0][0] = __builtin_amdgcn_mfma_f32_16x16x32_f16(a0, b0, acc[0][0], 0, 0, 0);
        acc[1][0] = __builtin_amdgcn_mfma_f32_16x16x32_f16(a1, b0, acc[1][0], 0, 0, 0);
        acc[0][1] = __builtin_amdgcn_mfma_f32_16x16x32_f16(a0, bb, acc[0][1], 0, 0, 0);
        acc[1][1] = __builtin_amdgcn_mfma_f32_16x16x32_f16(a1, bb, acc[1][1], 0, 0, 0);
    }

    if constexpr (OUT_MODE == 1) {
        __shared__ f16 ct[64][68];
#pragma unroll
        for (int sub = 0; sub < 2; ++sub)
#pragma unroll
            for (int snb = 0; snb < 2; ++snb) {
                const int nl = (w >> 1) * 32 + snb * 16 + col;
                const float bv = b1[nb + snb * 16 + col];
                const int ml0 = (w & 1) * 32 + sub * 16 + quad * 4;
                uint2 u;
                u.x = pack_f16x2(acc[sub][snb][0] + bv, acc[sub][snb][1] + bv);
                u.y = pack_f16x2(acc[sub][snb][2] + bv, acc[sub][snb][3] + bv);
                *reinterpret_cast<uint2*>(&ct[nl][ml0]) = u;
            }
        __syncthreads();
        const int nl = t >> 2, qtr = t & 3;
        const int n = bx * 64 + nl;
        const int m0 = by * 64 + qtr * 16;
        const f16x8 v0 = *reinterpret_cast<const f16x8*>(&ct[nl][qtr * 16]);
        const f16x8 v1 = *reinterpret_cast<const f16x8*>(&ct[nl][qtr * 16 + 8]);
        *reinterpret_cast<f16x8*>(&((f16*)outp)[(size_t)n * M + m0]) = v0;
        *reinterpret_cast<f16x8*>(&((f16*)outp)[(size_t)n * M + m0 + 8]) = v1;
    } else {
#pragma unroll
        for (int sub = 0; sub < 2; ++sub)
#pragma unroll
            for (int snb = 0; snb < 2; ++snb) {
                const int n = nb + snb * 16 + col;
                float bv = 0.f;
                if (OUT_MODE != 3)
                    bv = (DUAL_BIAS && n >= 256) ? b2[n - 256] : b1[n];
                if (OUT_MODE == 0) {
#pragma unroll
                    for (int reg = 0; reg < 4; ++reg) {
                        const int m = mb + sub * 16 + quad * 4 + reg;
                        const float v  = acc[sub][snb][reg] + bv;
                        const float v2 = __shfl_xor(v, 1);
                        if ((lane & 1) == 0)
                            *reinterpret_cast<unsigned int*>(
                                &((f16*)outp)[(size_t)m * N + (n & ~1)]) = pack_f16x2(v, v2);
                    }
                } else {
                    float* ob = (float*)outp + (size_t)bz * M * N;
#pragma unroll
                    for (int reg = 0; reg < 4; ++reg) {
                        const int m = mb + sub * 16 + quad * 4 + reg;
                        ob[(size_t)m * N + n] = acc[sub][snb][reg] + bv;
                    }
                }
            }
    }
}

// ---- fused QK + V projections --------------------------------------------
__global__ __launch_bounds__(256) void proj_kernel(
    const f16* __restrict__ xf, const f16* __restrict__ Wqkt,
    const f16* __restrict__ Wvt,
    const float* __restrict__ bq, const float* __restrict__ bk,
    const float* __restrict__ bv,
    f16* __restrict__ QKf, f16* __restrict__ Vtp) {
    if (blockIdx.x < 8)
        gemm_body<0, true>(xf, Wqkt, bq, bk, QKf, N_NODES, 512, D_MODEL,
                           blockIdx.x, blockIdx.y, 0, 1);
    else
        gemm_body<1, false>(xf, Wvt, bv, bv, Vtp, N_NODES, VH, D_MODEL,
                            blockIdx.x - 8, blockIdx.y, 0, 1);
}

// ---- out-projection with k-split -----------------------------------------
__global__ __launch_bounds__(256) void outproj_kernel(
    const f16* __restrict__ Rf, const f16* __restrict__ Wot,
    float* __restrict__ outp) {
    gemm_body<3, false>(Rf, Wot, nullptr, nullptr, outp, N_NODES, D_MODEL, VH,
                        blockIdx.x, blockIdx.y, blockIdx.z, gridDim.z);
}

// ---- barrier-free MFMA flash attention, fixed-max softmax ----------------
// 1D grid, h0 blocks FIRST with z=8 key-split; h!=0 z=4. Block = 4 waves;
// wave w owns queries [q0+32w, q0+32w+32) x ALL 128 d -> P round-trips
// through a WAVE-PRIVATE LDS slab (no __syncthreads anywhere). Row sums via
// ones-MFMA (C rows match O rows -> in-wave normalization). K/V/bias frags
// direct from global (L2-resident).
__global__ __launch_bounds__(256) void attn_kernel(
    const f16* __restrict__ QKf, const f16* __restrict__ Vt,
    const u64* __restrict__ mbits, const float* __restrict__ bias,
    f16* __restrict__ R, f16* __restrict__ part, float* __restrict__ lsum,
    int fancy) {
    const int b = blockIdx.x, t = threadIdx.x;
    const int w = t >> 6, lane = t & 63, quad = lane >> 4, col = lane & 15;

    int h, q0, jbegin, jend, seg;
    if (fancy) {
        if (b < 256) {            // head 0, 8-way key split, dispatched first
            h = 0; const int z = b >> 5; q0 = (b & 31) * 128;
            jbegin = z * 512; jend = jbegin + 512; seg = z;
        } else {
            const int e = b - 256;
            h = 1 + (e >> 7); const int r = e & 127;
            const int z = r >> 5; q0 = (r & 31) * 128;
            jbegin = z * 1024; jend = jbegin + 1024;
            seg = 8 + (h - 1) * 4 + z;
        }
    } else {
        h = b >> 5; q0 = (b & 31) * 128; jbegin = 0; jend = N_NODES; seg = 0;
    }

    __shared__ f16 ps[4][32][72];   // wave-private P slabs, 144B rows

    f16x8 qa[2];
#pragma unroll
    for (int qs = 0; qs < 2; ++qs)
        qa[qs] = *reinterpret_cast<const f16x8*>(
            &QKf[(size_t)(q0 + 32 * w + 16 * qs + col) * 512 + h * 32 + quad * 8]);

    const f32x4 zero = {0.f, 0.f, 0.f, 0.f};
    f32x4 O[2][8];                  // [qs][dt]; rows quad*4+reg, d 16*dt+col
#pragma unroll
    for (int qs = 0; qs < 2; ++qs)
#pragma unroll
        for (int dt = 0; dt < 8; ++dt) O[qs][dt] = zero;
    f32x4 Lacc[2];
    Lacc[0] = zero; Lacc[1] = zero;
    const f16 one1 = (f16)1.f;
    const f16x8 onesv = {one1, one1, one1, one1, one1, one1, one1, one1};

    const float scale = 0.17677669529663687f;   // 1/sqrt(32)
    const float MFIX = 8.f;

#pragma unroll 1
    for (int j0 = jbegin; j0 < jend; j0 += 64) {
        // K frags: MFMA #km covers keys {4n+km} -> lane's 4 scores are 4
        // consecutive keys -> one contiguous 8B ps write per (qs,reg)
        f16x8 kb[4];
#pragma unroll
        for (int km = 0; km < 4; ++km)
            kb[km] = *reinterpret_cast<const f16x8*>(
                &QKf[(size_t)(j0 + 4 * col + km) * 512 + 256 + h * 32 + quad * 8]);

        u64 mr[2][4];
#pragma unroll
        for (int qs = 0; qs < 2; ++qs)
#pragma unroll
            for (int reg = 0; reg < 4; ++reg)
                mr[qs][reg] = mbits[(size_t)(q0 + 32 * w + 16 * qs + quad * 4 + reg) * 64 +
                                    (j0 >> 6)];
        float bf[2][4][4];
        if (h == 0) {
#pragma unroll
            for (int qs = 0; qs < 2; ++qs)
#pragma unroll
                for (int reg = 0; reg < 4; ++reg) {
                    const float4 b4 = *reinterpret_cast<const float4*>(
                        &bias[(size_t)(q0 + 32 * w + 16 * qs + quad * 4 + reg) * N_NODES +
                              j0 + 4 * col]);
                    bf[qs][reg][0] = b4.x; bf[qs][reg][1] = b4.y;
                    bf[qs][reg][2] = b4.z; bf[qs][reg][3] = b4.w;
                }
        } else {
#pragma unroll
            for (int qs = 0; qs < 2; ++qs)
#pragma unroll
                for (int reg = 0; reg < 4; ++reg)
#pragma unroll
                    for (int km = 0; km < 4; ++km) bf[qs][reg][km] = 0.f;
        }

        // QK^T
        f32x4 S[2][4];
#pragma unroll
        for (int qs = 0; qs < 2; ++qs)
#pragma unroll
            for (int km = 0; km < 4; ++km)
                S[qs][km] = __builtin_amdgcn_mfma_f32_16x16x32_f16(qa[qs], kb[km], zero, 0, 0, 0);

        // p = exp(s-8), masked->0; wave-private ps write (no barrier)
#pragma unroll
        for (int qs = 0; qs < 2; ++qs)
#pragma unroll
            for (int reg = 0; reg < 4; ++reg) {
                float p[4];
#pragma unroll
                for (int km = 0; km < 4; ++km) {
                    const float s = S[qs][km][reg] * scale + bf[qs][reg][km];
                    const bool masked = (mr[qs][reg] >> (4 * col + km)) & 1ull;
                    p[km] = masked ? 0.f : __expf(s - MFIX);
                }
                uint2 u;
                u.x = pack_f16x2(p[0], p[1]);
                u.y = pack_f16x2(p[2], p[3]);
                *reinterpret_cast<uint2*>(
                    &ps[w][16 * qs + quad * 4 + reg][4 * col]) = u;
            }

        // read back in A-layout (in-wave lgkmcnt dependency only)
        f16x8 pa[2][2];
#pragma unroll
        for (int qs = 0; qs < 2; ++qs)
#pragma unroll
            for (int ks = 0; ks < 2; ++ks)
                pa[qs][ks] = *reinterpret_cast<const f16x8*>(
                    &ps[w][16 * qs + col][ks * 32 + quad * 8]);

#pragma unroll
        for (int qs = 0; qs < 2; ++qs) {
            Lacc[qs] = __builtin_amdgcn_mfma_f32_16x16x32_f16(pa[qs][0], onesv, Lacc[qs], 0, 0, 0);
            Lacc[qs] = __builtin_amdgcn_mfma_f32_16x16x32_f16(pa[qs][1], onesv, Lacc[qs], 0, 0, 0);
        }

        // PV over all 128 d (wave-independent)
#pragma unroll
        for (int dt = 0; dt < 8; ++dt) {
            const size_t vrow = (size_t)(h * 128 + 16 * dt + col) * N_NODES + j0;
            const f16x8 vb0 = *reinterpret_cast<const f16x8*>(&Vt[vrow + quad * 8]);
            const f16x8 vb1 = *reinterpret_cast<const f16x8*>(&Vt[vrow + 32 + quad * 8]);
#pragma unroll
            for (int qs = 0; qs < 2; ++qs) {
                O[qs][dt] = __builtin_amdgcn_mfma_f32_16x16x32_f16(pa[qs][0], vb0, O[qs][dt], 0, 0, 0);
                O[qs][dt] = __builtin_amdgcn_mfma_f32_16x16x32_f16(pa[qs][1], vb1, O[qs][dt], 0, 0, 0);
            }
        }
    }

    // in-wave normalize + store
#pragma unroll
    for (int qs = 0; qs < 2; ++qs)
#pragma unroll
        for (int reg = 0; reg < 4; ++reg) {
            const float inv = 1.f / Lacc[qs][reg];
            const int q = q0 + 32 * w + 16 * qs + quad * 4 + reg;
            if (fancy) {
#pragma unroll
                for (int dt = 0; dt < 8; ++dt)
                    part[((size_t)seg * N_NODES + q) * 128 + 16 * dt + col] =
                        (f16)(O[qs][dt][reg] * inv);
                if (col == 0) lsum[(size_t)seg * N_NODES + q] = Lacc[qs][reg];
            } else {
#pragma unroll
                for (int dt = 0; dt < 8; ++dt)
                    R[(size_t)q * VH + h * 128 + 16 * dt + col] =
                        (f16)(O[qs][dt][reg] * inv);
            }
        }
}

// ---- merge: R = sum_seg l*Obar / sum_seg l (h0: 8 segs, else 4) ----------
__global__ __launch_bounds__(256) void merge_kernel(
    const f16* __restrict__ part, const float* __restrict__ lsum,
    f16* __restrict__ R) {
    const int tid = blockIdx.x * 256 + threadIdx.x;   // 8*4096*128
    const int d = tid & 127, q = (tid >> 7) & 4095, h = tid >> 19;
    const int base = (h == 0) ? 0 : 8 + (h - 1) * 4;
    const int cnt  = (h == 0) ? 8 : 4;
    float num = 0.f, den = 0.f;
    for (int i = 0; i < cnt; ++i) {
        const size_t s = (size_t)(base + i) * N_NODES + q;
        const float l = lsum[s];
        num += l * (float)part[s * 128 + d];
        den += l;
    }
    R[(size_t)q * VH + h * 128 + d] = (f16)(num / den);
}

// ---- reduce out-proj k-split partials + bias ------------------------------
__global__ __launch_bounds__(256) void reduce_out_kernel(
    const float* __restrict__ part, const float* __restrict__ bo,
    float* __restrict__ out) {
    const int i = blockIdx.x * 256 + threadIdx.x;     // 4096*128
    float s = bo[i & 127];
#pragma unroll
    for (int z = 0; z < 4; ++z) s += part[(size_t)z * N_NODES * D_MODEL + i];
    out[i] = s;
}

extern "C" void kernel_launch(void* const* d_in, const int* in_sizes, int n_in,
                              void* d_out, int out_size, void* d_ws, size_t ws_size,
                              hipStream_t stream) {
    const float* x  = (const float*)d_in[0];
    const int*   mk = (const int*)d_in[1];
    const float* eb = (const float*)d_in[2];
    const float* Wq = (const float*)d_in[3];
    const float* bq = (const float*)d_in[4];
    const float* Wk = (const float*)d_in[5];
    const float* bk = (const float*)d_in[6];
    const float* Wv = (const float*)d_in[7];
    const float* bv = (const float*)d_in[8];
    const float* Wo = (const float*)d_in[9];
    const float* bo = (const float*)d_in[10];
    float* out = (float*)d_out;

    // layout with liveness overlap (out_part overlays dead prep/proj bufs):
    char* ws = (char*)d_ws;
    u64* mbits = (u64*)(ws);                    // [0, 2097152)          dead after attn
    f16* xf16  = (f16*)(ws + 2097152);          // +1 MB  -> 3145728     dead after proj
    f16* Wqkt  = (f16*)(ws + 3145728);          // +128KB -> 3276800     dead after proj
    f16* Wvt   = (f16*)(ws + 3276800);          // +256KB -> 3538944     dead after proj
    f16* QKf   = (f16*)(ws + 3538944);          // +4 MB  -> 7733248     dead after attn
    f16* Vt    = (f16*)(ws + 7733248);          // +8 MB  -> 16121856    dead after attn
    f16* Rf    = (f16*)(ws + 16121856);         // +8 MB  -> 24510464
    f16* Wot   = (f16*)(ws + 24510464);         // +256KB -> 24772608
    float* lsum = (float*)(ws + 24772608);      // +576KB -> 25362432
    f16* part  = (f16*)(ws + 25362432);         // +36 MB -> 63111168
    float* out_part = (float*)(ws);             // overlay [0, 8 MB), used post-attn

    const int fancy = (ws_size >= 63111168ull) ? 1 : 0;

    prep_kernel<<<2560, 256, 0, stream>>>(mk, mbits, x, xf16, Wq, Wk, Wqkt, Wv, Wvt, Wo, Wot);

    proj_kernel<<<dim3(24, 64), 256, 0, stream>>>(xf16, Wqkt, Wvt, bq, bk, bv, QKf, Vt);

    attn_kernel<<<fancy ? 1152 : 256, 256, 0, stream>>>(
        QKf, Vt, mbits, eb, Rf, part, lsum, fancy);
    if (fancy)
        merge_kernel<<<16384, 256, 0, stream>>>(part, lsum, Rf);

    outproj_kernel<<<dim3(2, 64, 4), 256, 0, stream>>>(Rf, Wot, out_part);
    reduce_out_kernel<<<2048, 256, 0, stream>>>(out_part, bo, out);
}